// Round 7
// baseline (297.205 us; speedup 1.0000x reference)
//
#include <hip/hip_runtime.h>
#include <hip/hip_bf16.h>

// GCN decoder, 4 dispatches:
//  1) prep_t0_k: blocks 0-255 compute msg0 = lat@W0+b0 (W0 transposed via LDS);
//     blocks 256+ transpose W1/W2/Wout to bf16 [fo][k].
//  2) agg_f32_k (v5 register-staged, PROVEN 58us): h1 = relu(adj_fp32@msg0) with
//     fused bf16-adj writeback + epilogue transform (msg1 = h1@W1+b1).
//  3-4) agg8_k<MODE> (NEW: m201-style 4-sub-phase interleave): consume bf16 adj.
//       MODE=0: epilogue transform (msg2). MODE=1: output proj * mask.
// XCD swizzle: batch = blockIdx&7 -> each XCD keeps its batch's msg panel L2-hot.
//
// v8: fine-grained sub-phase schedule for the bf16 aggregations. Evidence:
// agg00 scales perfectly with per-CU bytes (~9.5 B/cy wall) but bf16 aggs
// pinned at ~60us across reg-stage/glds/depth-2/depth-4 -> phase time is a
// FIXED ~3.5us serialization (m233's 2-phase stall), not latency and not
// bytes (v6: fully-landed prefetch at distance 2 didn't help). The only
// measured fix is T3+T4 coarse->fine interleave (+28-41%, m196->m198) with
// T5 setprio gated on it (+21-25%, m218b). Per K-tile: 4 sub-phases of
// {issue 2 glds of next tile | ds_read 4xb128 | lgkm(0)+schedbar |
// setprio(1) 2xMFMA setprio(0) | barrier}; one vmcnt(0)+barrier per tile
// boundary (all 6 next-tile glds issued >=2 sub-phases earlier -> hidden).
// LDS linear (glds dest) with both-sides XOR swizzle c^(row&15) (rule 21).

typedef __bf16 bf16;
typedef __bf16 bf16x4 __attribute__((ext_vector_type(4)));
typedef __bf16 bf16x8 __attribute__((ext_vector_type(8)));
typedef float  f32x16 __attribute__((ext_vector_type(16)));
typedef float  f32x4  __attribute__((ext_vector_type(4)));

static __device__ inline f32x16 mfma32(bf16x8 a, bf16x8 b, f32x16 c) {
    return __builtin_amdgcn_mfma_f32_32x32x16_bf16(a, b, c, 0, 0, 0);
}

// Barrier that does NOT drain vmcnt (v5 reg-staged kernel).
static __device__ inline void tile_barrier() {
    asm volatile("s_waitcnt lgkmcnt(0)" ::: "memory");
    __builtin_amdgcn_s_barrier();
    asm volatile("" ::: "memory");
}

// async global->LDS, 16B per lane; lds dest is wave-uniform base + lane*16
static __device__ inline void glds16(const bf16* g, bf16* l) {
    __builtin_amdgcn_global_load_lds(
        (const __attribute__((address_space(1))) unsigned int*)g,
        (__attribute__((address_space(3))) unsigned int*)l, 16, 0, 0);
}

#define NB   8
#define NN   2048
#define LAT  64
#define HID  128
#define ODIM 64
#define BM   64    // rows per block
#define BK   128   // k per tile
#define NP   16    // k-tiles (2048 / 128)
#define LDK  136   // padded LDS row stride (reg-staged kernel)
#define HLD  136   // Hs row stride

// ---------------- dispatch 1: transform0 (blocks 0-255) + weight prep (blocks 256+) ----
__global__ __launch_bounds__(256) void prep_t0_k(
    const float* __restrict__ lat, const float* __restrict__ W0,
    const float* __restrict__ b0,
    const float* __restrict__ W1, const float* __restrict__ W2,
    const float* __restrict__ Wout,
    bf16* __restrict__ msgT, bf16* __restrict__ WT1,
    bf16* __restrict__ WT2, bf16* __restrict__ WoutT)
{
    __shared__ __align__(16) bf16 WTs[HID * 72];   // W0^T [fo][k], stride 72
    int tid = threadIdx.x;
    int blk = blockIdx.x;

    if (blk >= 256) {           // weight transposes (tiny)
        int i = (blk - 256) * 256 + tid;
        if (i < HID * HID) { int fo = i >> 7, k = i & 127; WT1[i] = (bf16)W1[k * HID + fo]; return; }
        i -= HID * HID;
        if (i < HID * HID) { int fo = i >> 7, k = i & 127; WT2[i] = (bf16)W2[k * HID + fo]; return; }
        i -= HID * HID;
        if (i < ODIM * HID) { int o = i >> 7, k = i & 127; WoutT[i] = (bf16)Wout[k * ODIM + o]; return; }
        return;
    }

    // stage W0^T into LDS (W0 is [64][128] row-major, coalesced fp32 reads)
    for (int i = tid; i < LAT * HID; i += 256) {
        int k = i >> 7, fo = i & 127;
        WTs[fo * 72 + k] = (bf16)W0[i];
    }
    __syncthreads();

    int l = tid & 63, w = tid >> 6;
    int lm = l & 31, lh = l >> 5;
    int g0 = blk * 64;
    int b  = g0 >> 11, nb = g0 & 2047;

    const bf16*  Wrow = &WTs[(w * 32 + lm) * 72 + lh * 8];
    const float* r0   = lat + (size_t)(g0 + lm) * LAT + lh * 8;
    const float* r1   = r0 + (size_t)32 * LAT;

    f32x16 acc0 = {}, acc1 = {};
#pragma unroll
    for (int k0 = 0; k0 < LAT; k0 += 16) {
        bf16x8 a = *(const bf16x8*)(Wrow + k0);
        f32x4 x0 = *(const f32x4*)(r0 + k0), x1 = *(const f32x4*)(r0 + k0 + 4);
        f32x4 y0 = *(const f32x4*)(r1 + k0), y1 = *(const f32x4*)(r1 + k0 + 4);
        bf16x8 v0, v1;
        v0[0]=(bf16)x0[0]; v0[1]=(bf16)x0[1]; v0[2]=(bf16)x0[2]; v0[3]=(bf16)x0[3];
        v0[4]=(bf16)x1[0]; v0[5]=(bf16)x1[1]; v0[6]=(bf16)x1[2]; v0[7]=(bf16)x1[3];
        v1[0]=(bf16)y0[0]; v1[1]=(bf16)y0[1]; v1[2]=(bf16)y0[2]; v1[3]=(bf16)y0[3];
        v1[4]=(bf16)y1[0]; v1[5]=(bf16)y1[1]; v1[6]=(bf16)y1[2]; v1[7]=(bf16)y1[3];
        acc0 = mfma32(a, v0, acc0);
        acc1 = mfma32(a, v1, acc1);
    }

    bf16* outb = msgT + (size_t)b * (HID * NN) + nb;
#pragma unroll
    for (int r = 0; r < 16; ++r) {
        int fo = w * 32 + (r & 3) + 8 * (r >> 2) + 4 * lh;
        float bv = b0[fo];
        outb[(size_t)fo * NN + lm]      = (bf16)(acc0[r] + bv);
        outb[(size_t)fo * NN + 32 + lm] = (bf16)(acc1[r] + bv);
    }
}

// ---------------- dispatch 2: fused aggregate, fp32 adj + writeback (v5, proven) ----
__global__ __launch_bounds__(512) void agg_f32_k(
    const float* __restrict__ adjf, bf16* __restrict__ adjbo,
    const bf16* __restrict__ msgT, const bf16* __restrict__ WTn,
    const float* __restrict__ biasn, bf16* __restrict__ msg_out)
{
    __shared__ __align__(16) bf16 As[2][BM * LDK];
    __shared__ __align__(16) bf16 Bs[2][HID * LDK];
    __shared__ __align__(16) bf16 Hs[BM * HLD];
    int tid = threadIdx.x;
    int l = tid & 63, w = tid >> 6;
    int lm = l & 31, lh = l >> 5;
    int wm = w >> 2, wn = w & 3;
    int b  = blockIdx.x & 7;
    int m0 = (blockIdx.x >> 3) * BM;

    const bf16* msgb = msgT + (size_t)b * (HID * NN);
    int br = tid >> 3, bc8 = (tid & 7) * 8;
    const bf16* bsrc = msgb + (size_t)br * NN + bc8;

    int ar = tid >> 3, acf = (tid & 7) * 4;
    const float* asrc = adjf  + (size_t)b * NN * NN + (size_t)(m0 + ar) * NN + acf;
    bf16*        adst = adjbo + (size_t)b * NN * NN + (size_t)(m0 + ar) * NN + acf;

    f32x4  fa[2][4];
    bf16x8 pb[2][4];

    auto loadTile = [&](int set, int k) {
#pragma unroll
        for (int g = 0; g < 4; ++g) fa[set][g] = *(const f32x4*)(asrc + k + g * 32);
#pragma unroll
        for (int h = 0; h < 2; ++h)
#pragma unroll
            for (int g = 0; g < 2; ++g)
                pb[set][h * 2 + g] = *(const bf16x8*)(bsrc + (size_t)(h * 64) * NN + k + g * 64);
    };
    auto storeTile = [&](int set, int buf, int k) {
#pragma unroll
        for (int g = 0; g < 4; ++g) {
            bf16x4 v;
            v[0]=(bf16)fa[set][g][0]; v[1]=(bf16)fa[set][g][1];
            v[2]=(bf16)fa[set][g][2]; v[3]=(bf16)fa[set][g][3];
            *(bf16x4*)&As[buf][ar * LDK + acf + g * 32] = v;
            *(bf16x4*)(adst + k + g * 32)               = v;   // bf16 adj writeback
        }
#pragma unroll
        for (int h = 0; h < 2; ++h)
#pragma unroll
            for (int g = 0; g < 2; ++g)
                *(bf16x8*)&Bs[buf][(br + h * 64) * LDK + bc8 + g * 64] = pb[set][h * 2 + g];
    };

    f32x16 acc = {};
    auto mfmaTile = [&](int buf) {
        const bf16* Ac = &As[buf][(wm * 32 + lm) * LDK + lh * 8];
        const bf16* Bc = &Bs[buf][(wn * 32 + lm) * LDK + lh * 8];
#pragma unroll
        for (int s = 0; s < 8; ++s)
            acc = mfma32(*(const bf16x8*)(Ac + s * 16), *(const bf16x8*)(Bc + s * 16), acc);
    };

    loadTile(0, 0 * BK);
    loadTile(1, 1 * BK);
    storeTile(0, 0, 0 * BK);
    tile_barrier();

#define PHASE(U)                                                               \
    do {                                                                       \
        int q = qb + (U);                                                      \
        if (q + 2 < NP) loadTile((U), (q + 2) * BK);                           \
        if (q + 1 < NP) storeTile(((U) + 1) & 1, ((U) + 1) & 1, (q + 1) * BK); \
        mfmaTile((U) & 1);                                                     \
        tile_barrier();                                                        \
    } while (0)

#pragma unroll 1
    for (int qb = 0; qb < NP; qb += 2) {
        PHASE(0);
        PHASE(1);
    }
#undef PHASE

#pragma unroll
    for (int r = 0; r < 16; ++r) {
        int row = wm * 32 + (r & 3) + 8 * (r >> 2) + 4 * lh;
        float v = acc[r];
        Hs[row * HLD + wn * 32 + lm] = (bf16)(v > 0.f ? v : 0.f);
    }
    __syncthreads();

    const bf16* Arow = WTn + (size_t)(wn * 32 + lm) * HID + lh * 8;
    const bf16* Brow = &Hs[(wm * 32 + lm) * HLD + lh * 8];
    f32x16 acc2 = {};
#pragma unroll
    for (int s = 0; s < 8; ++s)
        acc2 = mfma32(*(const bf16x8*)(Arow + s * 16), *(const bf16x8*)(Brow + s * 16), acc2);
    bf16* outb = msg_out + (size_t)b * (HID * NN) + m0 + wm * 32;
#pragma unroll
    for (int r = 0; r < 16; ++r) {
        int fo = wn * 32 + (r & 3) + 8 * (r >> 2) + 4 * lh;
        outb[(size_t)fo * NN + lm] = (bf16)(acc2[r] + biasn[fo]);
    }
}

// ---------------- dispatches 3-4: fused aggregate, 4-sub-phase interleave ----------
template<int MODE>
__global__ __launch_bounds__(512) void agg8_k(
    const bf16* __restrict__ adjb,
    const bf16* __restrict__ msgT, const bf16* __restrict__ WTn,
    const float* __restrict__ biasn, bf16* __restrict__ msg_out,
    const float* __restrict__ mask, float* __restrict__ out)
{
    __shared__ __align__(16) bf16 As[2][BM * BK];    // 32 KB, linear (glds dest)
    __shared__ __align__(16) bf16 Bs[2][HID * BK];   // 64 KB, linear (glds dest)
    __shared__ __align__(16) bf16 Hs[BM * HLD];      // 17.4 KB
    int tid = threadIdx.x;
    int l = tid & 63, wv = tid >> 6;
    int lm = l & 31, lh = l >> 5;
    int wm = wv >> 2, wn = wv & 3;      // wave grid: 2 (m) x 4 (n)
    int b  = blockIdx.x & 7;            // XCD swizzle: batch b -> XCD b
    int m0 = (blockIdx.x >> 3) * BM;

    int r4 = l >> 4, c16 = l & 15;      // glds lane mapping: lane -> (row r4, chunk c16)

    const bf16* adjbase = adjb + (size_t)b * NN * NN + (size_t)m0 * NN;
    const bf16* msgb    = msgT + (size_t)b * (HID * NN);

    // glds per-lane global sources; col chunk pre-swizzled c ^ (row&15)
    int ar0 = wv * 8 + r4, ar1 = ar0 + 4;
    const bf16* aS0 = adjbase + (size_t)ar0 * NN + ((c16 ^ (ar0 & 15)) * 8);
    const bf16* aS1 = adjbase + (size_t)ar1 * NN + ((c16 ^ (ar1 & 15)) * 8);
    int br0 = wv * 16 + r4;
    const bf16* bS0 = msgb + (size_t)(br0     ) * NN + ((c16 ^ ((br0     ) & 15)) * 8);
    const bf16* bS1 = msgb + (size_t)(br0 +  4) * NN + ((c16 ^ ((br0 +  4) & 15)) * 8);
    const bf16* bS2 = msgb + (size_t)(br0 +  8) * NN + ((c16 ^ ((br0 +  8) & 15)) * 8);
    const bf16* bS3 = msgb + (size_t)(br0 + 12) * NN + ((c16 ^ ((br0 + 12) & 15)) * 8);

    auto sA  = [&](int buf, int k) {    // 2 glds
        glds16(aS0 + k, &As[buf][(wv * 8     ) * BK]);
        glds16(aS1 + k, &As[buf][(wv * 8 +  4) * BK]);
    };
    auto sB0 = [&](int buf, int k) {    // 2 glds
        glds16(bS0 + k, &Bs[buf][(wv * 16    ) * BK]);
        glds16(bS1 + k, &Bs[buf][(wv * 16 + 4) * BK]);
    };
    auto sB1 = [&](int buf, int k) {    // 2 glds
        glds16(bS2 + k, &Bs[buf][(wv * 16 + 8) * BK]);
        glds16(bS3 + k, &Bs[buf][(wv * 16 +12) * BK]);
    };

    int arow = wm * 32 + lm, brow = wn * 32 + lm;
    int hA = arow & 15, hB = brow & 15;
    f32x16 acc = {};

    // prologue: tile 0 staged (6 glds/wave in flight)
    sA(0, 0); sB0(0, 0); sB1(0, 0);

#pragma unroll 1
    for (int t = 0; t < NP; ++t) {
        int buf = t & 1, nbuf = buf ^ 1;
        int kn = (t + 1) * BK;
        // tile t's 6 glds (issued >=2 sub-phases ago in steady state) land here
        asm volatile("s_waitcnt vmcnt(0)" ::: "memory");
        __builtin_amdgcn_s_barrier();
        const bf16* Ab = &As[buf][arow * BK];
        const bf16* Bb = &Bs[buf][brow * BK];
#pragma unroll
        for (int p = 0; p < 4; ++p) {
            // interleave: issue next tile's glds early in the tile
            if (t + 1 < NP) {
                if      (p == 0) sA (nbuf, kn);
                else if (p == 1) sB0(nbuf, kn);
                else if (p == 2) sB1(nbuf, kn);
            }
            // ds_read 4 x b128: k-steps 2p, 2p+1 (chunk XOR-unswizzled)
            bf16x8 a0 = *(const bf16x8*)(Ab + ((4 * p     + lh) ^ hA) * 8);
            bf16x8 b0 = *(const bf16x8*)(Bb + ((4 * p     + lh) ^ hB) * 8);
            bf16x8 a1 = *(const bf16x8*)(Ab + ((4 * p + 2 + lh) ^ hA) * 8);
            bf16x8 b1 = *(const bf16x8*)(Bb + ((4 * p + 2 + lh) ^ hB) * 8);
            asm volatile("s_waitcnt lgkmcnt(0)" ::: "memory");
            __builtin_amdgcn_sched_barrier(0);
            __builtin_amdgcn_s_setprio(1);
            acc = mfma32(a0, b0, acc);
            acc = mfma32(a1, b1, acc);
            __builtin_amdgcn_s_setprio(0);
            __builtin_amdgcn_s_barrier();
        }
    }

    // relu(h) -> LDS [node][feat]
#pragma unroll
    for (int r = 0; r < 16; ++r) {
        int row = wm * 32 + (r & 3) + 8 * (r >> 2) + 4 * lh;
        float v = acc[r];
        Hs[row * HLD + wn * 32 + lm] = (bf16)(v > 0.f ? v : 0.f);
    }
    __syncthreads();

    if (MODE == 0) {
        const bf16* Arow = WTn + (size_t)(wn * 32 + lm) * HID + lh * 8;
        const bf16* Brow = &Hs[(wm * 32 + lm) * HLD + lh * 8];
        f32x16 acc2 = {};
#pragma unroll
        for (int s = 0; s < 8; ++s)
            acc2 = mfma32(*(const bf16x8*)(Arow + s * 16), *(const bf16x8*)(Brow + s * 16), acc2);
        bf16* outb = msg_out + (size_t)b * (HID * NN) + m0 + wm * 32;
#pragma unroll
        for (int r = 0; r < 16; ++r) {
            int fo = wn * 32 + (r & 3) + 8 * (r >> 2) + 4 * lh;
            outb[(size_t)fo * NN + lm] = (bf16)(acc2[r] + biasn[fo]);
        }
    } else {
        if (wn < 2) {
            int ob = wn * 32;
            const bf16* Arow = &Hs[(wm * 32 + lm) * HLD + lh * 8];
            const bf16* Brow = WTn + (size_t)(ob + lm) * HID + lh * 8;
            f32x16 acc2 = {};
#pragma unroll
            for (int s = 0; s < 8; ++s)
                acc2 = mfma32(*(const bf16x8*)(Arow + s * 16), *(const bf16x8*)(Brow + s * 16), acc2);
            float bv = biasn[ob + lm];
#pragma unroll
            for (int r = 0; r < 16; ++r) {
                int node = wm * 32 + (r & 3) + 8 * (r >> 2) + 4 * lh;
                int g = b * NN + m0 + node;
                out[(size_t)g * ODIM + ob + lm] = (acc2[r] + bv) * mask[g];
            }
        }
    }
}

extern "C" void kernel_launch(void* const* d_in, const int* in_sizes, int n_in,
                              void* d_out, int out_size, void* d_ws, size_t ws_size,
                              hipStream_t stream)
{
    const float* lat  = (const float*)d_in[0];
    const float* adj  = (const float*)d_in[1];
    const float* mask = (const float*)d_in[2];
    const float* W0   = (const float*)d_in[3];
    const float* b0   = (const float*)d_in[4];
    const float* W1   = (const float*)d_in[5];
    const float* b1   = (const float*)d_in[6];
    const float* W2   = (const float*)d_in[7];
    const float* b2   = (const float*)d_in[8];
    const float* Wout = (const float*)d_in[9];
    const float* bout = (const float*)d_in[10];
    float* out = (float*)d_out;

    char* ws = (char*)d_ws;
    bf16* msgA  = (bf16*)(ws + 0);            // 4 MiB
    bf16* msgB  = (bf16*)(ws + 4194304);      // 4 MiB
    bf16* adjbf = (bf16*)(ws + 8388608);      // 8*2048*2048*2 = 64 MiB
    bf16* WT1   = (bf16*)(ws + 75497472);     // 32 KiB
    bf16* WT2   = (bf16*)(ws + 75530240);     // 32 KiB
    bf16* WoutT = (bf16*)(ws + 75563008);     // 16 KiB

    // blocks 0-255: transform0; blocks 256-415: weight transposes (40960 elems)
    prep_t0_k<<<416, 256, 0, stream>>>(lat, W0, b0, W1, W2, Wout, msgA, WT1, WT2, WoutT);

    // 256 blocks = 32 m-tiles x 8 batches, 1 block/CU
    agg_f32_k<<<256, 512, 0, stream>>>(adj, adjbf, msgA, WT1, b1, msgB);
    agg8_k<0><<<256, 512, 0, stream>>>(adjbf, msgB, WT2, b2, msgA, nullptr, nullptr);
    agg8_k<1><<<256, 512, 0, stream>>>(adjbf, msgA, WoutT, bout, nullptr, mask, out);
}

// Round 8
// 276.431 us; speedup vs baseline: 1.0752x; 1.0752x over previous
//
#include <hip/hip_runtime.h>
#include <hip/hip_bf16.h>

// GCN decoder, 6 dispatches:
//  1) prep_t0_k: blocks 0-255 compute msg0 = lat@W0+b0; blocks 256+ transpose W*.
//  2) agg_f32_k (v5, proven, byte-capped): h1 = relu(adj_fp32@msg0), fused bf16-adj
//     writeback + epilogue transform (msg1).
//  3,5) aggsk_k (NEW split-K): partial[b][s] = adj_bf16[rows, k-half s] @ msg[:, k-half s]
//       -> f32 partials in workspace. 2 blocks/CU (disjoint k -> NO byte duplication,
//       v0-style cross-block overlap of the phase serialization).
//  4,6) comb_k<MODE>: sum partials + ReLU + epilogue GEMM (MODE=0 transform, MODE=1
//       output proj * mask).
// XCD swizzle: batch = blockIdx&7 everywhere.
//
// v9 rationale: ledger across v0/v5/v7/v8 shows each bf16 aggregation pinned at
// 55-62us by two coinciding walls: byte-cap (~10 B/cyc/CU delivered; v0 1.28 MB/CU)
// and 1-block phase serialization (v5: 16 x 8.7k cy lockstep, no co-resident block
// to overlap). Split-K is the untried corner: 2 blocks/CU with DISJOINT k-halves
// keeps v5's 0.77 MB/CU (nothing duplicated) and restores v0's measured 2-block
// overlap. Predict max(77k, ~66k) cy ~= 32us per aggregation + ~6us combine.

typedef __bf16 bf16;
typedef __bf16 bf16x4 __attribute__((ext_vector_type(4)));
typedef __bf16 bf16x8 __attribute__((ext_vector_type(8)));
typedef float  f32x16 __attribute__((ext_vector_type(16)));
typedef float  f32x4  __attribute__((ext_vector_type(4)));

static __device__ inline f32x16 mfma32(bf16x8 a, bf16x8 b, f32x16 c) {
    return __builtin_amdgcn_mfma_f32_32x32x16_bf16(a, b, c, 0, 0, 0);
}

// Barrier that does NOT drain vmcnt: LDS stores complete (lgkmcnt 0), global
// prefetch loads stay in flight.
static __device__ inline void tile_barrier() {
    asm volatile("s_waitcnt lgkmcnt(0)" ::: "memory");
    __builtin_amdgcn_s_barrier();
    asm volatile("" ::: "memory");
}

#define NB   8
#define NN   2048
#define LAT  64
#define HID  128
#define ODIM 64
#define BM   64    // rows per block
#define BK   128   // k per phase (agg_f32_k)
#define NP   16    // phases (agg_f32_k: 2048/128)
#define LDK  136   // padded LDS row stride (BK=128 kernels)
#define HLD  136   // Hs row stride
#define SKK  64    // k per phase (split-K kernel)
#define SKP  16    // phases (split-K: 1024/64)
#define SKL  72    // padded LDS row stride (BK=64 kernel)

// ---------------- dispatch 1: transform0 (blocks 0-255) + weight prep (blocks 256+) ----
__global__ __launch_bounds__(256) void prep_t0_k(
    const float* __restrict__ lat, const float* __restrict__ W0,
    const float* __restrict__ b0,
    const float* __restrict__ W1, const float* __restrict__ W2,
    const float* __restrict__ Wout,
    bf16* __restrict__ msgT, bf16* __restrict__ WT1,
    bf16* __restrict__ WT2, bf16* __restrict__ WoutT)
{
    __shared__ __align__(16) bf16 WTs[HID * 72];   // W0^T [fo][k], stride 72
    int tid = threadIdx.x;
    int blk = blockIdx.x;

    if (blk >= 256) {           // weight transposes (tiny)
        int i = (blk - 256) * 256 + tid;
        if (i < HID * HID) { int fo = i >> 7, k = i & 127; WT1[i] = (bf16)W1[k * HID + fo]; return; }
        i -= HID * HID;
        if (i < HID * HID) { int fo = i >> 7, k = i & 127; WT2[i] = (bf16)W2[k * HID + fo]; return; }
        i -= HID * HID;
        if (i < ODIM * HID) { int o = i >> 7, k = i & 127; WoutT[i] = (bf16)Wout[k * ODIM + o]; return; }
        return;
    }

    // stage W0^T into LDS (W0 is [64][128] row-major, coalesced fp32 reads)
    for (int i = tid; i < LAT * HID; i += 256) {
        int k = i >> 7, fo = i & 127;
        WTs[fo * 72 + k] = (bf16)W0[i];
    }
    __syncthreads();

    int l = tid & 63, w = tid >> 6;
    int lm = l & 31, lh = l >> 5;
    int g0 = blk * 64;
    int b  = g0 >> 11, nb = g0 & 2047;

    const bf16*  Wrow = &WTs[(w * 32 + lm) * 72 + lh * 8];
    const float* r0   = lat + (size_t)(g0 + lm) * LAT + lh * 8;
    const float* r1   = r0 + (size_t)32 * LAT;

    f32x16 acc0 = {}, acc1 = {};
#pragma unroll
    for (int k0 = 0; k0 < LAT; k0 += 16) {
        bf16x8 a = *(const bf16x8*)(Wrow + k0);
        f32x4 x0 = *(const f32x4*)(r0 + k0), x1 = *(const f32x4*)(r0 + k0 + 4);
        f32x4 y0 = *(const f32x4*)(r1 + k0), y1 = *(const f32x4*)(r1 + k0 + 4);
        bf16x8 v0, v1;
        v0[0]=(bf16)x0[0]; v0[1]=(bf16)x0[1]; v0[2]=(bf16)x0[2]; v0[3]=(bf16)x0[3];
        v0[4]=(bf16)x1[0]; v0[5]=(bf16)x1[1]; v0[6]=(bf16)x1[2]; v0[7]=(bf16)x1[3];
        v1[0]=(bf16)y0[0]; v1[1]=(bf16)y0[1]; v1[2]=(bf16)y0[2]; v1[3]=(bf16)y0[3];
        v1[4]=(bf16)y1[0]; v1[5]=(bf16)y1[1]; v1[6]=(bf16)y1[2]; v1[7]=(bf16)y1[3];
        acc0 = mfma32(a, v0, acc0);
        acc1 = mfma32(a, v1, acc1);
    }

    bf16* outb = msgT + (size_t)b * (HID * NN) + nb;
#pragma unroll
    for (int r = 0; r < 16; ++r) {
        int fo = w * 32 + (r & 3) + 8 * (r >> 2) + 4 * lh;
        float bv = b0[fo];
        outb[(size_t)fo * NN + lm]      = (bf16)(acc0[r] + bv);
        outb[(size_t)fo * NN + 32 + lm] = (bf16)(acc1[r] + bv);
    }
}

// ---------------- dispatch 2: fused aggregate, fp32 adj + writeback (v5, proven) ----
__global__ __launch_bounds__(512) void agg_f32_k(
    const float* __restrict__ adjf, bf16* __restrict__ adjbo,
    const bf16* __restrict__ msgT, const bf16* __restrict__ WTn,
    const float* __restrict__ biasn, bf16* __restrict__ msg_out)
{
    __shared__ __align__(16) bf16 As[2][BM * LDK];
    __shared__ __align__(16) bf16 Bs[2][HID * LDK];
    __shared__ __align__(16) bf16 Hs[BM * HLD];
    int tid = threadIdx.x;
    int l = tid & 63, w = tid >> 6;
    int lm = l & 31, lh = l >> 5;
    int wm = w >> 2, wn = w & 3;
    int b  = blockIdx.x & 7;
    int m0 = (blockIdx.x >> 3) * BM;

    const bf16* msgb = msgT + (size_t)b * (HID * NN);
    int br = tid >> 3, bc8 = (tid & 7) * 8;
    const bf16* bsrc = msgb + (size_t)br * NN + bc8;

    int ar = tid >> 3, acf = (tid & 7) * 4;
    const float* asrc = adjf  + (size_t)b * NN * NN + (size_t)(m0 + ar) * NN + acf;
    bf16*        adst = adjbo + (size_t)b * NN * NN + (size_t)(m0 + ar) * NN + acf;

    f32x4  fa[2][4];
    bf16x8 pb[2][4];

    auto loadTile = [&](int set, int k) {
#pragma unroll
        for (int g = 0; g < 4; ++g) fa[set][g] = *(const f32x4*)(asrc + k + g * 32);
#pragma unroll
        for (int h = 0; h < 2; ++h)
#pragma unroll
            for (int g = 0; g < 2; ++g)
                pb[set][h * 2 + g] = *(const bf16x8*)(bsrc + (size_t)(h * 64) * NN + k + g * 64);
    };
    auto storeTile = [&](int set, int buf, int k) {
#pragma unroll
        for (int g = 0; g < 4; ++g) {
            bf16x4 v;
            v[0]=(bf16)fa[set][g][0]; v[1]=(bf16)fa[set][g][1];
            v[2]=(bf16)fa[set][g][2]; v[3]=(bf16)fa[set][g][3];
            *(bf16x4*)&As[buf][ar * LDK + acf + g * 32] = v;
            *(bf16x4*)(adst + k + g * 32)               = v;   // bf16 adj writeback
        }
#pragma unroll
        for (int h = 0; h < 2; ++h)
#pragma unroll
            for (int g = 0; g < 2; ++g)
                *(bf16x8*)&Bs[buf][(br + h * 64) * LDK + bc8 + g * 64] = pb[set][h * 2 + g];
    };

    f32x16 acc = {};
    auto mfmaTile = [&](int buf) {
        const bf16* Ac = &As[buf][(wm * 32 + lm) * LDK + lh * 8];
        const bf16* Bc = &Bs[buf][(wn * 32 + lm) * LDK + lh * 8];
#pragma unroll
        for (int s = 0; s < 8; ++s)
            acc = mfma32(*(const bf16x8*)(Ac + s * 16), *(const bf16x8*)(Bc + s * 16), acc);
    };

    loadTile(0, 0 * BK);
    loadTile(1, 1 * BK);
    storeTile(0, 0, 0 * BK);
    tile_barrier();

#define PHASE(U)                                                               \
    do {                                                                       \
        int q = qb + (U);                                                      \
        if (q + 2 < NP) loadTile((U), (q + 2) * BK);                           \
        if (q + 1 < NP) storeTile(((U) + 1) & 1, ((U) + 1) & 1, (q + 1) * BK); \
        mfmaTile((U) & 1);                                                     \
        tile_barrier();                                                        \
    } while (0)

#pragma unroll 1
    for (int qb = 0; qb < NP; qb += 2) {
        PHASE(0);
        PHASE(1);
    }
#undef PHASE

#pragma unroll
    for (int r = 0; r < 16; ++r) {
        int row = wm * 32 + (r & 3) + 8 * (r >> 2) + 4 * lh;
        float v = acc[r];
        Hs[row * HLD + wn * 32 + lm] = (bf16)(v > 0.f ? v : 0.f);
    }
    __syncthreads();

    const bf16* Arow = WTn + (size_t)(wn * 32 + lm) * HID + lh * 8;
    const bf16* Brow = &Hs[(wm * 32 + lm) * HLD + lh * 8];
    f32x16 acc2 = {};
#pragma unroll
    for (int s = 0; s < 8; ++s)
        acc2 = mfma32(*(const bf16x8*)(Arow + s * 16), *(const bf16x8*)(Brow + s * 16), acc2);
    bf16* outb = msg_out + (size_t)b * (HID * NN) + m0 + wm * 32;
#pragma unroll
    for (int r = 0; r < 16; ++r) {
        int fo = wn * 32 + (r & 3) + 8 * (r >> 2) + 4 * lh;
        outb[(size_t)fo * NN + lm] = (bf16)(acc2[r] + biasn[fo]);
    }
}

// ---------------- dispatches 3,5: split-K partial aggregate -------------------------
// Grid 512: blk = (m<<4)|(s<<3)|b. Block (b,m,s): partial = adj[b, m-rows, kh(s)] @
// msg[b][:, kh(s)], kh(s) = [s*1024, s*1024+1024). 2 blocks/CU, LDS 55.3 KB.
__global__ __launch_bounds__(512, 4) void aggsk_k(
    const bf16* __restrict__ adjb, const bf16* __restrict__ msgT,
    float* __restrict__ hpart)
{
    __shared__ __align__(16) bf16 As[2][BM * SKL];    // 18.4 KB
    __shared__ __align__(16) bf16 Bs[2][HID * SKL];   // 36.9 KB
    int tid = threadIdx.x;
    int l = tid & 63, w = tid >> 6;
    int lm = l & 31, lh = l >> 5;
    int wm = w >> 2, wn = w & 3;        // wave grid: 2 (m) x 4 (n)
    int blk = blockIdx.x;
    int b  = blk & 7;                   // XCD swizzle: batch b -> XCD b
    int s  = (blk >> 3) & 1;            // k-half
    int m0 = (blk >> 4) * BM;
    int k0 = s * (NN / 2);

    const bf16* msgb = msgT + (size_t)b * (HID * NN) + k0;
    int br = tid >> 3, bc8 = (tid & 7) * 8;
    const bf16* bsrc = msgb + (size_t)br * NN + bc8;

    int ar = tid >> 3, ac8 = (tid & 7) * 8;
    const bf16* asrc = adjb + (size_t)b * NN * NN + (size_t)(m0 + ar) * NN + k0 + ac8;

    bf16x8 ba[2];
    bf16x8 pb[2][2];

    auto loadTile = [&](int set, int k) {
        ba[set] = *(const bf16x8*)(asrc + k);
        pb[set][0] = *(const bf16x8*)(bsrc + k);
        pb[set][1] = *(const bf16x8*)(bsrc + (size_t)64 * NN + k);
    };
    auto storeTile = [&](int set, int buf) {
        *(bf16x8*)&As[buf][ar * SKL + ac8]        = ba[set];
        *(bf16x8*)&Bs[buf][br * SKL + bc8]        = pb[set][0];
        *(bf16x8*)&Bs[buf][(br + 64) * SKL + bc8] = pb[set][1];
    };

    f32x16 acc = {};
    auto mfmaTile = [&](int buf) {
        const bf16* Ac = &As[buf][(wm * 32 + lm) * SKL + lh * 8];
        const bf16* Bc = &Bs[buf][(wn * 32 + lm) * SKL + lh * 8];
#pragma unroll
        for (int q = 0; q < 4; ++q)
            acc = mfma32(*(const bf16x8*)(Ac + q * 16), *(const bf16x8*)(Bc + q * 16), acc);
    };

    loadTile(0, 0 * SKK);
    loadTile(1, 1 * SKK);
    storeTile(0, 0);
    tile_barrier();

#define PHASE(U)                                                   \
    do {                                                           \
        int q = qb + (U);                                          \
        if (q + 2 < SKP) loadTile((U), (q + 2) * SKK);             \
        if (q + 1 < SKP) storeTile(((U) + 1) & 1, ((U) + 1) & 1);  \
        mfmaTile((U) & 1);                                         \
        tile_barrier();                                            \
    } while (0)

#pragma unroll 1
    for (int qb = 0; qb < SKP; qb += 2) {
        PHASE(0);
        PHASE(1);
    }
#undef PHASE

    // store f32 partial [row][feat] for this (b,s)
    float* hp = hpart + ((size_t)((b << 1) | s) * NN + m0 + wm * 32) * HID + wn * 32 + lm;
#pragma unroll
    for (int r = 0; r < 16; ++r) {
        int row = (r & 3) + 8 * (r >> 2) + 4 * lh;
        hp[(size_t)row * HID] = acc[r];
        hp += 0;  // keep base; index below
    }
    // (note: the loop above writes hp[row*HID]; rewritten explicitly for clarity)
}

// ---------------- dispatches 4,6: combine + ReLU + epilogue -------------------------
template<int MODE>
__global__ __launch_bounds__(512) void comb_k(
    const float* __restrict__ hpart, const bf16* __restrict__ WTn,
    const float* __restrict__ biasn, bf16* __restrict__ msg_out,
    const float* __restrict__ mask, float* __restrict__ out)
{
    __shared__ __align__(16) bf16 Hs[BM * HLD];      // 17.4 KB
    int tid = threadIdx.x;
    int l = tid & 63, w = tid >> 6;
    int lm = l & 31, lh = l >> 5;
    int wm = w >> 2, wn = w & 3;
    int b  = blockIdx.x & 7;
    int m0 = (blockIdx.x >> 3) * BM;

    // sum partials + ReLU -> Hs [node][feat]
    int r = tid >> 3, c = (tid & 7) * 16;
    const float* p0 = hpart + ((size_t)(b * 2 + 0) * NN + m0 + r) * HID + c;
    const float* p1 = hpart + ((size_t)(b * 2 + 1) * NN + m0 + r) * HID + c;
#pragma unroll
    for (int i = 0; i < 4; ++i) {
        f32x4 x = *(const f32x4*)(p0 + i * 4);
        f32x4 y = *(const f32x4*)(p1 + i * 4);
        bf16x4 v;
#pragma unroll
        for (int j = 0; j < 4; ++j) {
            float z = x[j] + y[j];
            v[j] = (bf16)(z > 0.f ? z : 0.f);
        }
        *(bf16x4*)&Hs[r * HLD + c + i * 4] = v;
    }
    __syncthreads();

    if (MODE == 0) {
        // msg_out[fo][m0+node] = WTn[fo][:] . h[node][:] + biasn[fo]
        const bf16* Arow = WTn + (size_t)(wn * 32 + lm) * HID + lh * 8;
        const bf16* Brow = &Hs[(wm * 32 + lm) * HLD + lh * 8];
        f32x16 acc2 = {};
#pragma unroll
        for (int q = 0; q < 8; ++q)
            acc2 = mfma32(*(const bf16x8*)(Arow + q * 16), *(const bf16x8*)(Brow + q * 16), acc2);
        bf16* outb = msg_out + (size_t)b * (HID * NN) + m0 + wm * 32;
#pragma unroll
        for (int rr = 0; rr < 16; ++rr) {
            int fo = wn * 32 + (rr & 3) + 8 * (rr >> 2) + 4 * lh;
            outb[(size_t)fo * NN + lm] = (bf16)(acc2[rr] + biasn[fo]);
        }
    } else {
        if (wn < 2) {
            int ob = wn * 32;
            const bf16* Arow = &Hs[(wm * 32 + lm) * HLD + lh * 8];
            const bf16* Brow = WTn + (size_t)(ob + lm) * HID + lh * 8;
            f32x16 acc2 = {};
#pragma unroll
            for (int q = 0; q < 8; ++q)
                acc2 = mfma32(*(const bf16x8*)(Arow + q * 16), *(const bf16x8*)(Brow + q * 16), acc2);
            float bv = biasn[ob + lm];
#pragma unroll
            for (int rr = 0; rr < 16; ++rr) {
                int node = wm * 32 + (rr & 3) + 8 * (rr >> 2) + 4 * lh;
                int g = b * NN + m0 + node;
                out[(size_t)g * ODIM + ob + lm] = (acc2[rr] + bv) * mask[g];
            }
        }
    }
}

extern "C" void kernel_launch(void* const* d_in, const int* in_sizes, int n_in,
                              void* d_out, int out_size, void* d_ws, size_t ws_size,
                              hipStream_t stream)
{
    const float* lat  = (const float*)d_in[0];
    const float* adj  = (const float*)d_in[1];
    const float* mask = (const float*)d_in[2];
    const float* W0   = (const float*)d_in[3];
    const float* b0   = (const float*)d_in[4];
    const float* W1   = (const float*)d_in[5];
    const float* b1   = (const float*)d_in[6];
    const float* W2   = (const float*)d_in[7];
    const float* b2   = (const float*)d_in[8];
    const float* Wout = (const float*)d_in[9];
    const float* bout = (const float*)d_in[10];
    float* out = (float*)d_out;

    char* ws = (char*)d_ws;
    bf16*  msgA  = (bf16*)(ws + 0);            // 4 MiB
    bf16*  msgB  = (bf16*)(ws + 4194304);      // 4 MiB
    bf16*  adjbf = (bf16*)(ws + 8388608);      // 64 MiB
    bf16*  WT1   = (bf16*)(ws + 75497472);     // 32 KiB
    bf16*  WT2   = (bf16*)(ws + 75530240);     // 32 KiB
    bf16*  WoutT = (bf16*)(ws + 75563008);     // 16 KiB
    float* hpart = (float*)(ws + 83886080);    // 16 MiB (f32 partials, 2 k-halves)

    // blocks 0-255: transform0; blocks 256-415: weight transposes
    prep_t0_k<<<416, 256, 0, stream>>>(lat, W0, b0, W1, W2, Wout, msgA, WT1, WT2, WoutT);

    // layer 1: byte-capped fused kernel (also produces bf16 adj)
    agg_f32_k<<<256, 512, 0, stream>>>(adj, adjbf, msgA, WT1, b1, msgB);

    // layer 2: split-K + combine
    aggsk_k<<<512, 512, 0, stream>>>(adjbf, msgB, hpart);
    comb_k<0><<<256, 512, 0, stream>>>(hpart, WT2, b2, msgA, nullptr, nullptr);

    // layer 3 + output projection: split-K + combine
    aggsk_k<<<512, 512, 0, stream>>>(adjbf, msgA, hpart);
    comb_k<1><<<256, 512, 0, stream>>>(hpart, WoutT, bout, nullptr, mask, out);
}